// Round 1
// baseline (160.087 us; speedup 1.0000x reference)
//
#include <hip/hip_runtime.h>
#include <math.h>

// KAN layer forward, MI355X.
// NUM_IN = NUM_OUT = 128, SIZE = 16384, BATCH = 512, K = 3 (cubic), G = 5.
//
// Reference semantics:
//   s = o*128 + i ;  pre_acts[s,b]   = x[b,i]
//   post_splines[s,b] = mask[s] * sum_j coef[s,j] * B3_j(x[b,i]; grid_s)
//   post_acts[s,b]    = scale_b[s]*silu(x[b,i]) + scale_spline[s]*post_splines[s,b]
//   y[b,i] = sum_o post_acts[o*128+i, b]
// Outputs concatenated: y (512*128), pre_acts.T, post_splines.T, post_acts.T
// (each 512*16384, layout [b][s]).
//
// The grid is uniform (linspace extended with constant h), so the cubic
// B-spline basis reduces to the closed-form uniform weights on the 4-wide
// support window [m-3, m] where m = floor((x - e0)/h). h and e0 are derived
// from the actual knots[s] values each iteration; out-of-range x (all-zero
// basis in the reference) and truncated boundary windows (j outside [0,7])
// are handled explicitly, matching the truncated Cox-de Boor recursion.

#define N_IN   128
#define SIZEK  16384
#define BATCH  512

#define TB 4    // batches per thread
#define CO 16   // o-values per thread

__global__ __launch_bounds__(256) void kan_fwd(
    const float* __restrict__ x,            // [512][128]
    const float* __restrict__ scale_b,      // [16384]
    const float* __restrict__ scale_spline, // [16384]
    const float* __restrict__ coef,         // [16384][8]
    const float* __restrict__ mask,         // [16384]
    const float* __restrict__ knots,        // [16384][6]
    float* __restrict__ y,                  // [512][128] (pre-zeroed)
    float* __restrict__ pre_out,            // [512][16384]
    float* __restrict__ spl_out,            // [512][16384]
    float* __restrict__ post_out)           // [512][16384]
{
    const int g  = blockIdx.x * blockDim.x + threadIdx.x;
    const int i  = g & 127;          // input index (lane-consecutive -> coalesced)
    const int r  = g >> 7;
    const int oc = r & 7;            // o-chunk id (8 chunks of 16)
    const int bg = r >> 3;           // batch-group id (128 groups of 4)
    const int o0 = oc << 4;
    const int b0 = bg << 2;

    float xv[TB], sil[TB], ysum[TB];
#pragma unroll
    for (int t = 0; t < TB; ++t) {
        const float xx = x[(b0 + t) * N_IN + i];
        xv[t]   = xx;
        sil[t]  = xx / (1.0f + __expf(-xx));   // silu(x) = x * sigmoid(x)
        ysum[t] = 0.0f;
    }

    for (int oo = 0; oo < CO; ++oo) {
        const int s = ((o0 + oo) << 7) | i;

        // per-edge scalars (shared across the TB batches)
        const float k0 = knots[s * 6];
        const float k5 = knots[s * 6 + 5];
        const float h    = (k5 - k0) * 0.2f;       // (g_last-g_first)/G, G=5
        const float invh = 1.0f / h;
        const float e0   = k0 - 3.0f * h;          // leftmost extended knot
        const float mk = mask[s];
        const float sb = scale_b[s];
        const float ss = scale_spline[s];
        const float* __restrict__ cs = coef + s * 8;

#pragma unroll
        for (int t = 0; t < TB; ++t) {
            const float u  = (xv[t] - e0) * invh;
            const float mf = floorf(u);
            const int   m  = (int)mf;
            const float tt = u - mf;               // fractional position in interval
            const bool inr = (m >= 0) && (m <= 10); // inside extended grid?

            const float t2  = tt * tt;
            const float t3  = t2 * tt;
            const float omt = 1.0f - tt;
            float w[4];
            w[0] = omt * omt * omt * (1.0f / 6.0f);
            w[1] = (3.0f * t3 - 6.0f * t2 + 4.0f) * (1.0f / 6.0f);
            w[2] = (-3.0f * t3 + 3.0f * t2 + 3.0f * tt + 1.0f) * (1.0f / 6.0f);
            w[3] = t3 * (1.0f / 6.0f);

            const int jlo = m - 3;
            float spline = 0.0f;
#pragma unroll
            for (int rr = 0; rr < 4; ++rr) {
                const int j  = jlo + rr;
                const int jc = min(max(j, 0), 7);   // clamp: keep load in-bounds
                const float c  = cs[jc];
                const float wv = (inr && j >= 0 && j <= 7) ? w[rr] : 0.0f;
                spline = fmaf(c, wv, spline);
            }

            const float splm = spline * mk;
            const float post = fmaf(sb, sil[t], ss * splm);

            const size_t idx = (size_t)(b0 + t) * SIZEK + (size_t)s;
            pre_out[idx]  = xv[t];
            spl_out[idx]  = splm;
            post_out[idx] = post;
            ysum[t] += post;
        }
    }

#pragma unroll
    for (int t = 0; t < TB; ++t)
        atomicAdd(&y[(b0 + t) * N_IN + i], ysum[t]);
}

extern "C" void kernel_launch(void* const* d_in, const int* in_sizes, int n_in,
                              void* d_out, int out_size, void* d_ws, size_t ws_size,
                              hipStream_t stream) {
    const float* x            = (const float*)d_in[0];
    const float* scale_b      = (const float*)d_in[1];
    const float* scale_spline = (const float*)d_in[2];
    const float* coef         = (const float*)d_in[3];
    const float* mask         = (const float*)d_in[4];
    const float* knots        = (const float*)d_in[5];

    float* out  = (float*)d_out;
    float* y    = out;                         // 512*128      = 65536
    float* pre  = y + 512 * 128;               // 512*16384    = 8388608
    float* spl  = pre + (size_t)512 * 16384;
    float* post = spl + (size_t)512 * 16384;

    // y is accumulated with atomics; harness poisons d_out with 0xAA.
    hipMemsetAsync(y, 0, 512 * 128 * sizeof(float), stream);

    // threads = 128 i * 8 o-chunks * 128 b-groups = 131072 -> 512 blocks
    dim3 grid(512), block(256);
    kan_fwd<<<grid, block, 0, stream>>>(x, scale_b, scale_spline, coef, mask,
                                        knots, y, pre, spl, post);
}